// Round 15
// baseline (34.017 us; speedup 1.0000x reference)
//
#include <hip/hip_runtime.h>
#include <cstdint>

// Problem constants (from setup_inputs: logits/targets [16,1,512,512] f32)
#define BB 16
#define HH 512
#define WW 512
#define NPIX (BB*HH*WW)          // 4194304
#define WR (HH/32)               // 16 word-rows per image
#define NWORDS (BB*WR*WW)        // 131072 u32 = 512 KB
#define NXCD 8
#define RPB 8                    // rows per block (8-aligned base: p0+7 <= 31)
#define NGRP (BB*HH/RPB)         // 1024 blocks
#define GCHUNK (NGRP/NXCD)       // 128

// ---------------------------------------------------------------------------
// Kernel 0: vertical bit-pack of targets, 2 words per thread via float2 loads.
// vmask[b][w][j] bit r = (targets[b][32w+r][j] > 0.5).  512 KB total.
// ---------------------------------------------------------------------------
__global__ __launch_bounds__(256) void packbits(const float* __restrict__ targets,
                                                uint32_t* __restrict__ vmask) {
    const int flat = blockIdx.x * 256 + threadIdx.x;   // 0..65535
    const int jp = (flat & 255) * 2;                   // even column
    const int w  = (flat >> 8) & (WR - 1);
    const int b  = flat >> 12;
    const float2* base =
        (const float2*)(targets + ((size_t)(b * HH + w * 32)) * WW + jp);
    uint32_t w0 = 0, w1 = 0;
    #pragma unroll
    for (int r = 0; r < 32; ++r) {
        const float2 q = base[r * (WW / 2)];
        w0 |= (q.x > 0.5f ? 1u : 0u) << r;
        w1 |= (q.y > 0.5f ? 1u : 0u) << r;
    }
    ((uint2*)vmask)[flat] = make_uint2(w0, w1);        // 2*flat == b*8192+w*512+jp
}

// ---------------------------------------------------------------------------
// Fused kernel: one block per 8-ROW GROUP, 512 threads = one column each.
//  Phase 1 (per row, register-only): vertical distance d1 via 64-bit windows
//           (exact; word-scan fallback), PLUS in-row nearest-opposite via
//           __ballot (pure VALU, no memory) -> m0 = min(d1^2, inrow^2).
//           The ballot candidate caps m0 so the LDS tail is ~never needed.
//  Phase 2: packed (d<<1)|t in LDS [8][512]; branchless k=1..3 (6 ds_reads
//           per row — round-14 lesson: phase 2 is LDS-ISSUE-bound, k=1..7
//           branchless cost +7.6us); merged exact tail over all 8 rows while
//           k^2 < max_r m[r] (P ~ 0.8%/wave; exact: k >= sqrt(m) can't win,
//           opposite-class neighbors appear as dd=0 candidates).
//  Phase 3: p = clip(sigmoid) via rcp; v += p*sqrt(m); one reduce / 4096 px.
// No atomics/fences (round-7 lesson: device-scope fence chain = 204 us).
// ---------------------------------------------------------------------------
__global__ __launch_bounds__(512) void fused_row8(
        const uint32_t* __restrict__ vmask,
        const float* __restrict__ logits,
        float* __restrict__ partial) {
    const int bid = blockIdx.x;
    const int g   = (bid & (NXCD - 1)) * GCHUNK + (bid >> 3);  // bijective swizzle
    const int b   = g >> 6;                 // 64 groups per image
    const int i0  = (g & 63) << 3;          // first row of the group (8-aligned)
    const int j   = threadIdx.x;
    const int w   = i0 >> 5;                // shared word-row (i0..i0+7 same word)
    const int p0  = i0 & 31;                // in {0,8,16,24}
    const int lane = j & 63;

    __shared__ uint32_t pk_s[RPB][WW];
    __shared__ float    sw[8];

    const uint32_t* vm = vmask + (size_t)b * WR * WW;

    const uint32_t Wse = vm[w * WW + j];
    const bool has_u = (w > 0), has_d = (w < WR - 1);
    const uint32_t Wup = has_u ? vm[(w - 1) * WW + j] : 0u;
    const uint32_t Wdn = has_d ? vm[(w + 1) * WW + j] : 0u;

    // logits for the 8 pixels (independent coalesced loads, overlap phase 1)
    float xs[RPB];
    #pragma unroll
    for (int r = 0; r < RPB; ++r)
        xs[r] = logits[((size_t)(b * HH + i0 + r)) * WW + j];

    // class-agnostic 64-bit windows; bit q of downfull <-> row 32w+q,
    // bit q of upfull <-> row 32w-32+q. Valid masks zero out-of-image words.
    const uint64_t downfull = (uint64_t)Wse | ((uint64_t)Wdn << 32);
    const uint64_t upfull   = ((uint64_t)Wse << 32) | (uint64_t)Wup;
    const uint64_t dvalid = 0x00000000FFFFFFFFull |
                            (has_d ? 0xFFFFFFFF00000000ull : 0ull);
    const uint64_t uvalid = 0xFFFFFFFF00000000ull |
                            (has_u ? 0x00000000FFFFFFFFull : 0ull);

    int tpx[RPB], mpx[RPB];
    #pragma unroll
    for (int r = 0; r < RPB; ++r) {
        const int p = p0 + r;               // <= 31
        const int i = i0 + r;
        const int t = (int)((Wse >> p) & 1u);
        const uint64_t tm64 = t ? ~0ull : 0ull;
        const uint32_t tm32 = t ? 0xFFFFFFFFu : 0u;

        // vertical distance (exact)
        const uint64_t Zd = ((downfull ^ tm64) & dvalid) >> (p + 1);   // shift <= 32
        const uint64_t Zu = ((upfull   ^ tm64) & uvalid) << (32 - p);  // shift in [1,32]
        int dd, du;
        if (Zd) {
            dd = __ffsll((unsigned long long)Zd);
        } else {                                       // essentially never
            dd = 1023;
            for (int ww = w + 2; ww < WR; ++ww) {
                const uint32_t Xw = vm[ww * WW + j] ^ tm32;
                if (Xw) { dd = 32 * ww + (__ffs(Xw) - 1) - i; break; }
            }
        }
        if (Zu) {
            du = __clzll((long long)Zu) + 1;
        } else {                                       // essentially never
            du = 1023;
            for (int ww = w - 2; ww >= 0; --ww) {
                const uint32_t Xw = vm[ww * WW + j] ^ tm32;
                if (Xw) { du = i - (32 * ww + 31 - __clz((int)Xw)); break; }
            }
        }
        const int d = min(min(dd, du), 1023);

        // in-row nearest opposite within the wave (register-only candidate)
        const uint64_t Ob = (uint64_t)__ballot(t != 0) ^ tm64;
        const uint64_t Zr = (lane < 63) ? (Ob >> (lane + 1)) : 0ull;
        const uint64_t Zl = (lane > 0)  ? (Ob << (64 - lane)) : 0ull;
        const int drr = Zr ? __ffsll((unsigned long long)Zr) : 1023;
        const int dll = Zl ? (__clzll((long long)Zl) + 1)     : 1023;
        const int inr = min(drr, dll);

        mpx[r] = min(d * d, inr * inr);
        tpx[r] = t;
        pk_s[r][j] = (uint32_t)((d << 1) | t);
    }
    __syncthreads();

    // ---- Phase 2: branchless k=1..3 per row ----
    #pragma unroll
    for (int r = 0; r < RPB; ++r) {
        const int t = tpx[r];
        const uint32_t* rowp = &pk_s[r][0];
        int m = mpx[r];
        #pragma unroll
        for (int k = 1; k <= 3; ++k) {
            const int jl = j - k, jr = j + k;
            const uint32_t pl = rowp[jl >= 0 ? jl : 0];
            const uint32_t pr = rowp[jr < WW ? jr : (WW - 1)];
            const int dl = ((int)(pl & 1u) == t) ? (int)(pl >> 1) : 0;
            const int dr = ((int)(pr & 1u) == t) ? (int)(pr >> 1) : 0;
            const int cl = (jl >= 0) ? (dl * dl + k * k) : 0x7fffffff;
            const int cr = (jr < WW) ? (dr * dr + k * k) : 0x7fffffff;
            m = min(m, min(cl, cr));
        }
        mpx[r] = m;
    }

    // ---- merged exact tail (P ~ 0.8% of waves) ----
    int mx = mpx[0];
    #pragma unroll
    for (int r = 1; r < RPB; ++r) mx = max(mx, mpx[r]);
    for (int k = 4; k * k < mx; ++k) {
        const int k2 = k * k;
        mx = 0;
        #pragma unroll
        for (int r = 0; r < RPB; ++r) {
            const int t = tpx[r];
            const uint32_t* rowp = &pk_s[r][0];
            const int jl = j - k, jr = j + k;
            const uint32_t pl = rowp[jl >= 0 ? jl : 0];
            const uint32_t pr = rowp[jr < WW ? jr : (WW - 1)];
            const int dl = ((int)(pl & 1u) == t) ? (int)(pl >> 1) : 0;
            const int dr = ((int)(pr & 1u) == t) ? (int)(pr >> 1) : 0;
            const int cl = (jl >= 0) ? (dl * dl + k2) : 0x7fffffff;
            const int cr = (jr < WW) ? (dr * dr + k2) : 0x7fffffff;
            const int m = min(mpx[r], min(cl, cr));
            mpx[r] = m;
            mx = max(mx, m);
        }
    }

    // ---- Phase 3: loss terms ----
    float v = 0.0f;
    #pragma unroll
    for (int r = 0; r < RPB; ++r) {
        const float dt = __builtin_amdgcn_sqrtf((float)mpx[r]);
        float pr = __builtin_amdgcn_rcpf(1.0f + __expf(-xs[r]));
        pr = fminf(fmaxf(pr, 1e-7f), (float)(1.0 - 1e-7));
        v += pr * dt;
    }

    // ---- block reduction (512 threads = 8 waves), one per 4096 px ----
    #pragma unroll
    for (int off = 32; off > 0; off >>= 1)
        v += __shfl_down(v, off);

    const int wid = threadIdx.x >> 6;
    if (lane == 0) sw[wid] = v;
    __syncthreads();
    if (threadIdx.x == 0) {
        float s = 0.0f;
        #pragma unroll
        for (int ww = 0; ww < 8; ++ww) s += sw[ww];
        partial[g] = s;
    }
}

// ---------------------------------------------------------------------------
// Deterministic final reduction of NGRP partials -> mean
// ---------------------------------------------------------------------------
__global__ __launch_bounds__(256) void finalreduce(
        const float* __restrict__ partial,
        float* __restrict__ out) {
    const float4 q = ((const float4*)partial)[threadIdx.x];   // 256*4 == 1024
    float v = (q.x + q.y) + (q.z + q.w);

    #pragma unroll
    for (int off = 32; off > 0; off >>= 1)
        v += __shfl_down(v, off);

    __shared__ float sw[4];
    const int lane = threadIdx.x & 63;
    const int wid  = threadIdx.x >> 6;
    if (lane == 0) sw[wid] = v;
    __syncthreads();
    if (threadIdx.x == 0)
        out[0] = ((sw[0] + sw[1]) + (sw[2] + sw[3])) * (1.0f / (float)NPIX);
}

extern "C" void kernel_launch(void* const* d_in, const int* in_sizes, int n_in,
                              void* d_out, int out_size, void* d_ws, size_t ws_size,
                              hipStream_t stream) {
    const float* logits  = (const float*)d_in[0];
    const float* targets = (const float*)d_in[1];
    float* out = (float*)d_out;

    // workspace layout: [ vmask u32 NWORDS (512KB) | partial float NGRP (4KB) ]
    uint32_t* vmask = (uint32_t*)d_ws;
    float* partial  = (float*)((char*)d_ws + (size_t)NWORDS * sizeof(uint32_t));

    packbits<<<NWORDS / 2 / 256, 256, 0, stream>>>(targets, vmask);
    fused_row8<<<NGRP, 512, 0, stream>>>(vmask, logits, partial);
    finalreduce<<<1, 256, 0, stream>>>(partial, out);
}

// Round 16
// 20.546 us; speedup vs baseline: 1.6556x; 1.6556x over previous
//
#include <hip/hip_runtime.h>
#include <cstdint>

// Problem constants (from setup_inputs: logits/targets [16,1,512,512] f32)
#define BB 16
#define HH 512
#define WW 512
#define NPIX (BB*HH*WW)          // 4194304
#define WR (HH/32)               // 16 word-rows per image
#define NWORDS (BB*WR*WW)        // 131072 u32 = 512 KB
#define NXCD 8
#define RPB 8                    // rows per block (8-aligned base: p0+7 <= 31)
#define NPAIR (RPB/2)            // 4 row-pairs per block
#define NGRP (BB*HH/RPB)         // 1024 blocks
#define GCHUNK (NGRP/NXCD)       // 128

// ---------------------------------------------------------------------------
// Kernel 0: vertical bit-pack of targets, 2 words per thread via float2 loads.
// vmask[b][w][j] bit r = (targets[b][32w+r][j] > 0.5).  512 KB total.
// ---------------------------------------------------------------------------
__global__ __launch_bounds__(256) void packbits(const float* __restrict__ targets,
                                                uint32_t* __restrict__ vmask) {
    const int flat = blockIdx.x * 256 + threadIdx.x;   // 0..65535
    const int jp = (flat & 255) * 2;                   // even column
    const int w  = (flat >> 8) & (WR - 1);
    const int b  = flat >> 12;
    const float2* base =
        (const float2*)(targets + ((size_t)(b * HH + w * 32)) * WW + jp);
    uint32_t w0 = 0, w1 = 0;
    #pragma unroll
    for (int r = 0; r < 32; ++r) {
        const float2 q = base[r * (WW / 2)];
        w0 |= (q.x > 0.5f ? 1u : 0u) << r;
        w1 |= (q.y > 0.5f ? 1u : 0u) << r;
    }
    ((uint2*)vmask)[flat] = make_uint2(w0, w1);        // 2*flat == b*8192+w*512+jp
}

// ---------------------------------------------------------------------------
// Fused kernel: one block per 8-ROW GROUP (8-aligned rows always share one
// 32-bit word-row), 512 threads = one column each, 8 pixels per thread.
//  Phase 1: the SAME 3 vmask words (self/up/down) serve all 8 rows; per row
//           shift/ffs/clz on 64-bit windows (exact; word-scan fallback).
//  Phase 2: TWO rows packed per LDS word (lo16/hi16, each (d<<1)|t, d<=1023
//           fits 12 bits) -> every ds_read serves 2 rows; 8 row-loops become
//           4 pair-loops (round-14/15 lesson: phase 2 is LDS-issue bound —
//           halve reads mechanically, don't add VALU candidates).
//           Unrolled k=1,2 + exact pair-merged divergent tail while
//           k^2 < max(m0,m1) (candidates cost >= k^2: can't improve a row
//           whose m <= k^2, so the merge is exact).
//  Phase 3: p = clip(sigmoid) via rcp; v += p*sqrt(m); one reduce / 4096 px.
// No atomics/fences (round-7 lesson: device-scope fence chain = 204 us).
// ---------------------------------------------------------------------------
__global__ __launch_bounds__(512) void fused_row8(
        const uint32_t* __restrict__ vmask,
        const float* __restrict__ logits,
        float* __restrict__ partial) {
    const int bid = blockIdx.x;
    const int g   = (bid & (NXCD - 1)) * GCHUNK + (bid >> 3);  // bijective swizzle
    const int b   = g >> 6;                 // 64 groups per image
    const int i0  = (g & 63) << 3;          // first row of the group (8-aligned)
    const int j   = threadIdx.x;
    const int w   = i0 >> 5;                // shared word-row (i0..i0+7 same word)
    const int p0  = i0 & 31;                // in {0,8,16,24}

    __shared__ uint32_t pk_s[NPAIR][WW];    // 8 KB
    __shared__ float    sw[8];

    const uint32_t* vm = vmask + (size_t)b * WR * WW;

    // one word-column triple serves all 8 rows
    const uint32_t Wse = vm[w * WW + j];
    const uint32_t Wup = (w > 0)      ? vm[(w - 1) * WW + j] : 0u;
    const uint32_t Wdn = (w < WR - 1) ? vm[(w + 1) * WW + j] : 0u;

    // logits for the 8 pixels (independent coalesced loads, overlap phase 1)
    float xs[RPB];
    #pragma unroll
    for (int r = 0; r < RPB; ++r)
        xs[r] = logits[((size_t)(b * HH + i0 + r)) * WW + j];

    int dpx[RPB], tpx[RPB];
    #pragma unroll
    for (int r = 0; r < RPB; ++r) {
        const int      p  = p0 + r;         // <= 31 always
        const int      i  = i0 + r;
        const int      t  = (int)((Wse >> p) & 1u);
        const uint32_t tm = t ? 0xFFFFFFFFu : 0u;
        const uint32_t Xs = Wse ^ tm;                              // 1 = opposite
        const uint32_t Xu = (w > 0)      ? (Wup ^ tm) : 0u;
        const uint32_t Xd = (w < WR - 1) ? (Wdn ^ tm) : 0u;

        // down window: bit q = row i+1+q (covers rows i+1 .. 32w+63)
        const uint64_t Zd = ((uint64_t)Xs >> (p + 1)) | ((uint64_t)Xd << (31 - p));
        // up window: bit 63 = row i-1, descending (covers rows 32w-32 .. i-1)
        const uint64_t Zu = (((uint64_t)Xs << 32) | (uint64_t)Xu) << (32 - p);

        int dd, du;
        if (Zd) {
            dd = __ffsll((unsigned long long)Zd);      // 1-based == distance
        } else {                                       // essentially never
            dd = 1023;
            for (int ww = w + 2; ww < WR; ++ww) {
                const uint32_t Xw = vm[ww * WW + j] ^ tm;
                if (Xw) { dd = 32 * ww + (__ffs(Xw) - 1) - i; break; }
            }
        }
        if (Zu) {
            du = __clzll((long long)Zu) + 1;
        } else {                                       // essentially never
            du = 1023;
            for (int ww = w - 2; ww >= 0; --ww) {
                const uint32_t Xw = vm[ww * WW + j] ^ tm;
                if (Xw) { du = i - (32 * ww + 31 - __clz((int)Xw)); break; }
            }
        }
        dpx[r] = min(min(dd, du), 1023);
        tpx[r] = t;
    }

    // pack two rows per LDS word: lo16 = row 2p, hi16 = row 2p+1
    #pragma unroll
    for (int pr = 0; pr < NPAIR; ++pr) {
        const uint32_t lo = (uint32_t)((dpx[2 * pr]     << 1) | tpx[2 * pr]);
        const uint32_t hi = (uint32_t)((dpx[2 * pr + 1] << 1) | tpx[2 * pr + 1]);
        pk_s[pr][j] = lo | (hi << 16);
    }
    __syncthreads();

    // ---- Phase 2: four pair-loops; each ds_read serves two rows ----
    int mpx[RPB];
    #pragma unroll
    for (int pr = 0; pr < NPAIR; ++pr) {
        const int t0 = tpx[2 * pr], t1 = tpx[2 * pr + 1];
        int m0 = dpx[2 * pr] * dpx[2 * pr];
        int m1 = dpx[2 * pr + 1] * dpx[2 * pr + 1];
        const uint32_t* rowp = &pk_s[pr][0];

        #pragma unroll
        for (int k = 1; k <= 2; ++k) {
            const int jl = j - k, jr = j + k;
            const int k2 = k * k;
            const uint32_t pl = rowp[jl >= 0 ? jl : 0];
            const uint32_t pr_ = rowp[jr < WW ? jr : (WW - 1)];
            const int d0l = ((int)(pl & 1u) == t0)          ? (int)((pl & 0xFFFFu) >> 1) : 0;
            const int d1l = ((int)((pl >> 16) & 1u) == t1)  ? (int)(pl >> 17)            : 0;
            const int d0r = ((int)(pr_ & 1u) == t0)         ? (int)((pr_ & 0xFFFFu) >> 1) : 0;
            const int d1r = ((int)((pr_ >> 16) & 1u) == t1) ? (int)(pr_ >> 17)           : 0;
            const int c0l = (jl >= 0) ? (d0l * d0l + k2) : 0x7fffffff;
            const int c1l = (jl >= 0) ? (d1l * d1l + k2) : 0x7fffffff;
            const int c0r = (jr < WW) ? (d0r * d0r + k2) : 0x7fffffff;
            const int c1r = (jr < WW) ? (d1r * d1r + k2) : 0x7fffffff;
            m0 = min(m0, min(c0l, c0r));
            m1 = min(m1, min(c1l, c1r));
        }

        // exact pair-merged divergent tail (avg ~1-3 wave iterations)
        {
            const int kmaxRow = max(j, WW - 1 - j);
            for (int k = 3; k <= kmaxRow && k * k < max(m0, m1); ++k) {
                const int k2 = k * k;
                if (k <= j) {
                    const uint32_t p2 = rowp[j - k];
                    const int e0 = ((int)(p2 & 1u) == t0)         ? (int)((p2 & 0xFFFFu) >> 1) : 0;
                    const int e1 = ((int)((p2 >> 16) & 1u) == t1) ? (int)(p2 >> 17)            : 0;
                    m0 = min(m0, e0 * e0 + k2);
                    m1 = min(m1, e1 * e1 + k2);
                }
                if (k <= WW - 1 - j) {
                    const uint32_t p2 = rowp[j + k];
                    const int e0 = ((int)(p2 & 1u) == t0)         ? (int)((p2 & 0xFFFFu) >> 1) : 0;
                    const int e1 = ((int)((p2 >> 16) & 1u) == t1) ? (int)(p2 >> 17)            : 0;
                    m0 = min(m0, e0 * e0 + k2);
                    m1 = min(m1, e1 * e1 + k2);
                }
            }
        }
        mpx[2 * pr] = m0;
        mpx[2 * pr + 1] = m1;
    }

    // ---- Phase 3: loss terms ----
    float v = 0.0f;
    #pragma unroll
    for (int r = 0; r < RPB; ++r) {
        const float dt = __builtin_amdgcn_sqrtf((float)mpx[r]);
        float pr = __builtin_amdgcn_rcpf(1.0f + __expf(-xs[r]));
        pr = fminf(fmaxf(pr, 1e-7f), (float)(1.0 - 1e-7));
        v += pr * dt;
    }

    // ---- block reduction (512 threads = 8 waves), one per 4096 px ----
    #pragma unroll
    for (int off = 32; off > 0; off >>= 1)
        v += __shfl_down(v, off);

    const int lane = threadIdx.x & 63;
    const int wid  = threadIdx.x >> 6;
    if (lane == 0) sw[wid] = v;
    __syncthreads();
    if (threadIdx.x == 0) {
        float s = 0.0f;
        #pragma unroll
        for (int ww = 0; ww < 8; ++ww) s += sw[ww];
        partial[g] = s;
    }
}

// ---------------------------------------------------------------------------
// Deterministic final reduction of NGRP partials -> mean
// ---------------------------------------------------------------------------
__global__ __launch_bounds__(256) void finalreduce(
        const float* __restrict__ partial,
        float* __restrict__ out) {
    const float4 q = ((const float4*)partial)[threadIdx.x];   // 256*4 == 1024
    float v = (q.x + q.y) + (q.z + q.w);

    #pragma unroll
    for (int off = 32; off > 0; off >>= 1)
        v += __shfl_down(v, off);

    __shared__ float sw[4];
    const int lane = threadIdx.x & 63;
    const int wid  = threadIdx.x >> 6;
    if (lane == 0) sw[wid] = v;
    __syncthreads();
    if (threadIdx.x == 0)
        out[0] = ((sw[0] + sw[1]) + (sw[2] + sw[3])) * (1.0f / (float)NPIX);
}

extern "C" void kernel_launch(void* const* d_in, const int* in_sizes, int n_in,
                              void* d_out, int out_size, void* d_ws, size_t ws_size,
                              hipStream_t stream) {
    const float* logits  = (const float*)d_in[0];
    const float* targets = (const float*)d_in[1];
    float* out = (float*)d_out;

    // workspace layout: [ vmask u32 NWORDS (512KB) | partial float NGRP (4KB) ]
    uint32_t* vmask = (uint32_t*)d_ws;
    float* partial  = (float*)((char*)d_ws + (size_t)NWORDS * sizeof(uint32_t));

    packbits<<<NWORDS / 2 / 256, 256, 0, stream>>>(targets, vmask);
    fused_row8<<<NGRP, 512, 0, stream>>>(vmask, logits, partial);
    finalreduce<<<1, 256, 0, stream>>>(partial, out);
}